// Round 11
// baseline (205.767 us; speedup 1.0000x reference)
//
#include <hip/hip_runtime.h>
#include <math.h>

#define BB 8
#define SS 32
#define HN 64
#define TN 512
#define HID 512

typedef __attribute__((ext_vector_type(8))) short short8;
typedef __attribute__((ext_vector_type(4))) float f32x4;

__device__ __forceinline__ float eluf(float x) { return x > 0.f ? x : (expf(x) - 1.f); }

__device__ __forceinline__ short f2bs(float f) {
    union { float f; unsigned int u; } v; v.f = f;
    unsigned int r = v.u + 0x7fffu + ((v.u >> 16) & 1u);
    return (short)(r >> 16);
}
__device__ __forceinline__ float b2f(short s) {
    union { unsigned int u; float f; } v;
    v.u = ((unsigned int)(unsigned short)s) << 16;
    return v.f;
}

__device__ __forceinline__ void gld16(const void* g, void* l) {
    __builtin_amdgcn_global_load_lds(
        (const __attribute__((address_space(1))) void*)g,
        (__attribute__((address_space(3))) void*)l, 16, 0, 0);
}

// ---------------------------------------------------------------------------
// 4-wave 128x128 GEMM core, BK=64: front-side GEMMs (qall/qe/tk/tkWT).
// Ls = 16384 shorts (32KB). OUTB: 0=f32, 1=bf16.  (verified baseline core)
// ---------------------------------------------------------------------------
template <int ACT, int OUTB>
__device__ __forceinline__ void gcore(
    const short* __restrict__ A, const short* __restrict__ B,
    const float* __restrict__ bias, void* __restrict__ Cv,
    int ldc, int K, int m0, int n0, int cm0, short* Ls)
{
    short* Al = Ls;
    short* Bl = Ls + 8192;
    const int tid  = threadIdx.x;
    const int lane = tid & 63;
    const int w    = tid >> 6;
    const int wr   = w >> 1, wc = w & 1;
    const int l16  = lane & 15, quad = lane >> 4;

    const int srow = w * 16 + (lane >> 2);
    const int scol = (lane & 3) * 8;

    f32x4 acc[4][4];
#pragma unroll
    for (int i = 0; i < 4; ++i)
#pragma unroll
        for (int j = 0; j < 4; ++j) { acc[i][j][0]=0.f; acc[i][j][1]=0.f; acc[i][j][2]=0.f; acc[i][j][3]=0.f; }

    short* lA = Al + w * 512;
    short* lB = Bl + w * 512;
    const long rstep = (long)64 * K;

    const short* Ag = A + (long)(m0 + srow) * K + scol;
    const short* Bg = B + (long)(n0 + srow) * K + scol;
    for (int kt = 0; kt < K; kt += 64) {
        __syncthreads();
        gld16(Ag + kt, lA);
        gld16(Ag + kt + rstep, lA + 2048);
        gld16(Ag + kt + 32, lA + 4096);
        gld16(Ag + kt + 32 + rstep, lA + 4096 + 2048);
        gld16(Bg + kt, lB);
        gld16(Bg + kt + rstep, lB + 2048);
        gld16(Bg + kt + 32, lB + 4096);
        gld16(Bg + kt + 32 + rstep, lB + 4096 + 2048);
        __syncthreads();
#pragma unroll
        for (int h = 0; h < 2; ++h) {
            short8 af[4], bf4[4];
#pragma unroll
            for (int mi = 0; mi < 4; ++mi)
                af[mi] = *(const short8*)(Al + h * 4096 + (wr * 64 + mi * 16 + l16) * 32 + quad * 8);
#pragma unroll
            for (int ni = 0; ni < 4; ++ni)
                bf4[ni] = *(const short8*)(Bl + h * 4096 + (wc * 64 + ni * 16 + l16) * 32 + quad * 8);
#pragma unroll
            for (int mi = 0; mi < 4; ++mi)
#pragma unroll
                for (int ni = 0; ni < 4; ++ni)
                    acc[mi][ni] = __builtin_amdgcn_mfma_f32_16x16x32_bf16(af[mi], bf4[ni], acc[mi][ni], 0, 0, 0);
        }
    }

    __syncthreads();

    float bv[4];
#pragma unroll
    for (int ni = 0; ni < 4; ++ni)
        bv[ni] = bias ? bias[n0 + wc * 64 + ni * 16 + l16] : 0.f;

    if (OUTB == 1) {
        short* eb = Ls + w * 1152;
        const int er = lane >> 2;
        const int ec = (lane & 3) * 16;
#pragma unroll
        for (int mi = 0; mi < 4; ++mi) {
#pragma unroll
            for (int ni = 0; ni < 4; ++ni)
#pragma unroll
                for (int r = 0; r < 4; ++r) {
                    float x = acc[mi][ni][r] + bv[ni];
                    if (ACT == 1) x = eluf(x);
                    eb[(quad * 4 + r) * 72 + ni * 16 + l16] = f2bs(x);
                }
            __builtin_amdgcn_sched_barrier(0);
            short8 v0 = *(const short8*)&eb[er * 72 + ec];
            short8 v1 = *(const short8*)&eb[er * 72 + ec + 8];
            long cb = (long)(cm0 + wr * 64 + mi * 16 + er) * ldc + n0 + wc * 64 + ec;
            *(short8*)((short*)Cv + cb)     = v0;
            *(short8*)((short*)Cv + cb + 8) = v1;
            __builtin_amdgcn_sched_barrier(0);
        }
    } else {
#pragma unroll
        for (int mi = 0; mi < 4; ++mi)
#pragma unroll
            for (int ni = 0; ni < 4; ++ni) {
                int gc = n0 + wc * 64 + ni * 16 + l16;
#pragma unroll
                for (int r = 0; r < 4; ++r) {
                    float x = acc[mi][ni][r] + bv[ni];
                    if (ACT == 1) x = eluf(x);
                    ((float*)Cv)[(long)(cm0 + wr * 64 + mi * 16 + quad * 4 + r) * ldc + gc] = x;
                }
            }
    }
}

// ---------------------------------------------------------------------------
// Tail LDS layout (shorts). Total 79872 shorts = 156 KB (<160 KB/CU, 1 blk/CU).
// ---------------------------------------------------------------------------
#define L_TQ   0
#define L_BST  32768
#define L_AST  65536
#define L_EB   69632
#define L_HQ   78848
#define L_TOT  79872

// ---------------------------------------------------------------------------
// Tail GEMM: C[64][512] += A[64][512] @ B[512][512]^T, BK=32, double-buffered
// staging with counted vmcnt (T3/T4), granule-XOR swizzled LDS (T2).
// AFT=1: A-fragments from persistent swizzled L_TQ. AFT=0: A staged (P panel).
// T5: s_setprio(1) around the MFMA cluster.
// ---------------------------------------------------------------------------
template <int AFT>
__device__ __forceinline__ void tgemmv(
    const short* __restrict__ Arows, const short* __restrict__ B,
    short* Ls, f32x4 (&acc)[4][4])
{
    const int tid  = threadIdx.x;
    const int lane = tid & 63;
    const int w    = tid >> 6;
    const int l16  = lane & 15, quad = lane >> 4;
    short* TQ  = Ls + L_TQ;
    short* BST = Ls + L_BST;
    short* AST = Ls + L_AST;

    auto STAGE = [&](int kt, int p) {
        short* Bl = BST + p * 16384;
#pragma unroll
        for (int j = 0; j < 4; ++j) {
            int lin = j * 512 + tid;
            int r = lin >> 2, gs = lin & 3;
            int g = gs ^ ((r >> 1) & 3);               // source-permuted granule
            gld16(B + (long)r * 512 + kt + g * 8, Bl + j * 4096 + w * 512);
        }
        if constexpr (AFT == 0) {
            if (tid < 256) {
                short* Al = AST + p * 2048;
                int r = tid >> 2, gs = tid & 3;
                int g = gs ^ ((r >> 1) & 3);
                gld16(Arows + (long)r * 512 + kt + g * 8, Al + w * 512);
            }
        }
    };

    STAGE(0, 0);
    int p = 0;
    for (int kt = 0; kt < 512; kt += 32, p ^= 1) {
        if (kt + 32 < 512) {
            STAGE(kt + 32, p ^ 1);
            if (AFT == 0 && w < 4) asm volatile("s_waitcnt vmcnt(5)" ::: "memory");
            else                   asm volatile("s_waitcnt vmcnt(4)" ::: "memory");
        } else {
            asm volatile("s_waitcnt vmcnt(0)" ::: "memory");
        }
        __builtin_amdgcn_s_barrier();
        __builtin_amdgcn_sched_barrier(0);

        short* Bl = BST + p * 16384;
        short8 af[4], bf[4];
#pragma unroll
        for (int mi = 0; mi < 4; ++mi) {
            int row = mi * 16 + l16;
            if constexpr (AFT == 1) {
                int slot = ((kt >> 3) + quad) ^ (row & 7);
                af[mi] = *(const short8*)(TQ + row * 512 + slot * 8);
            } else {
                short* Al = AST + p * 2048;
                int slot = quad ^ ((row >> 1) & 3);
                af[mi] = *(const short8*)(Al + row * 32 + slot * 8);
            }
        }
#pragma unroll
        for (int ni = 0; ni < 4; ++ni) {
            int row = w * 64 + ni * 16 + l16;
            int slot = quad ^ ((row >> 1) & 3);
            bf[ni] = *(const short8*)(Bl + row * 32 + slot * 8);
        }
        __builtin_amdgcn_s_setprio(1);
#pragma unroll
        for (int mi = 0; mi < 4; ++mi)
#pragma unroll
            for (int ni = 0; ni < 4; ++ni)
                acc[mi][ni] = __builtin_amdgcn_mfma_f32_16x16x32_bf16(af[mi], bf[ni], acc[mi][ni], 0, 0, 0);
        __builtin_amdgcn_s_setprio(0);
        asm volatile("s_waitcnt lgkmcnt(0)" ::: "memory");
        __builtin_amdgcn_s_barrier();
        __builtin_amdgcn_sched_barrier(0);
    }
}

// Epilogue: wave tile 64x64 -> bf16 rows via eb transpose (verified pattern).
// MODE 0: scores -> L_BST linear [64][512].  MODE 1: tanh -> L_TQ swizzled.
template <int MODE>
__device__ __forceinline__ void epi(f32x4 (&acc)[4][4], short* Ls)
{
    const int tid  = threadIdx.x;
    const int lane = tid & 63;
    const int w    = tid >> 6;
    const int l16  = lane & 15, quad = lane >> 4;
    short* eb = Ls + L_EB + w * 1152;
    const int er = lane >> 2;
    const int ec = (lane & 3) * 16;
#pragma unroll
    for (int mi = 0; mi < 4; ++mi) {
#pragma unroll
        for (int ni = 0; ni < 4; ++ni)
#pragma unroll
            for (int r = 0; r < 4; ++r) {
                float x = acc[mi][ni][r];
                if (MODE == 1) x = tanhf(x);
                eb[(quad * 4 + r) * 72 + ni * 16 + l16] = f2bs(x);
            }
        __builtin_amdgcn_sched_barrier(0);
        short8 v0 = *(const short8*)&eb[er * 72 + ec];
        short8 v1 = *(const short8*)&eb[er * 72 + ec + 8];
        int row = mi * 16 + er;
        if (MODE == 0) {
            short* SC = Ls + L_BST;
            *(short8*)(SC + row * 512 + w * 64 + ec)     = v0;
            *(short8*)(SC + row * 512 + w * 64 + ec + 8) = v1;
        } else {
            int g0 = (w * 64 + ec) >> 3;
            *(short8*)(Ls + L_TQ + row * 512 + ((g0)     ^ (row & 7)) * 8) = v0;
            *(short8*)(Ls + L_TQ + row * 512 + ((g0 + 1) ^ (row & 7)) * 8) = v1;
        }
        __builtin_amdgcn_sched_barrier(0);
    }
}

// ---------------------------------------------------------------------------
// Tail: one block per n=(b,s). (Round-5 structure + T5; unchanged from r10.)
// ---------------------------------------------------------------------------
__global__ __launch_bounds__(512, 1) void tail_kernel(
    const float* __restrict__ qall, const float* __restrict__ qe,
    const float* __restrict__ b_tq, const float* __restrict__ b_hq,
    const short* __restrict__ tkb, const short* __restrict__ tkWTb,
    const short* __restrict__ WT,
    const int* __restrict__ adj, const int* __restrict__ dup,
    const int* __restrict__ head, const float* __restrict__ b_hk,
    short* __restrict__ Pb, float* __restrict__ out)
{
    __shared__ short Ls[L_TOT];
    const int tid  = threadIdx.x;
    const int lane = tid & 63;
    const int w    = tid >> 6;
    const int l16  = lane & 15, quad = lane >> 4;

    // XCD swizzle: all 32 blocks of one b land on one XCD (round-robin bid%8).
    const int n = (blockIdx.x & 7) * 32 + (blockIdx.x >> 3);
    const int b = n >> 5;
    const int s = n & 31;
    const long rb = (long)n * 64;

    const short* tkb_b  = tkb + (long)b * 262144;
    const short* tkWT_b = tkWTb + (long)b * 262144;
    const short* WT7    = WT + (size_t)7 * 262144;
    const short* WT8    = WT + (size_t)8 * 262144;
    short* Prows = Pb + rb * 512;
    float* HQ = (float*)(Ls + L_HQ);

    // ---- phase 0: build tq rows (swizzled into L_TQ) + hq vector ----
    {
        const int cg = tid & 63;            // col granule
        const int wg = tid >> 6;            // row group (8 rows per wave)
        float4 qd0 = *(const float4*)(qall + (long)n * 2048 + cg * 8);
        float4 qd1 = *(const float4*)(qall + (long)n * 2048 + cg * 8 + 4);
        float4 qh0 = *(const float4*)(qall + (long)(256 + b) * 2048 + 1024 + cg * 8);
        float4 qh1 = *(const float4*)(qall + (long)(256 + b) * 2048 + 1024 + cg * 8 + 4);
        float4 bt0 = *(const float4*)(b_tq + cg * 8);
        float4 bt1 = *(const float4*)(b_tq + cg * 8 + 4);
        float base[8] = {qd0.x + qh0.x + bt0.x, qd0.y + qh0.y + bt0.y,
                         qd0.z + qh0.z + bt0.z, qd0.w + qh0.w + bt0.w,
                         qd1.x + qh1.x + bt1.x, qd1.y + qh1.y + bt1.y,
                         qd1.z + qh1.z + bt1.z, qd1.w + qh1.w + bt1.w};
#pragma unroll
        for (int i = 0; i < 8; ++i) {
            int h = wg * 8 + i;
            const float* er = qe + (long)(b * 64 + h) * 512 + cg * 8;
            float4 e0 = *(const float4*)er;
            float4 e1 = *(const float4*)(er + 4);
            float ev[8] = {e0.x, e0.y, e0.z, e0.w, e1.x, e1.y, e1.z, e1.w};
            short8 o;
#pragma unroll
            for (int u = 0; u < 8; ++u) o[u] = f2bs(eluf(base[u] + ev[u]));
            int slot = cg ^ (h & 7);
            *(short8*)(Ls + L_TQ + h * 512 + slot * 8) = o;
        }
        if (tid < 512) {
            HQ[tid] = eluf(qall[(long)n * 2048 + 512 + tid]
                         + qall[(long)(256 + b) * 2048 + 1536 + tid] + b_hq[tid]);
        }
    }
    __syncthreads();

    f32x4 acc[4][4];
#pragma unroll
    for (int i = 0; i < 4; ++i)
#pragma unroll
        for (int j = 0; j < 4; ++j) { acc[i][j][0]=0.f; acc[i][j][1]=0.f; acc[i][j][2]=0.f; acc[i][j][3]=0.f; }

    // ---- phase A: scores = tq @ tk_b^T -> L_BST linear ----
    tgemmv<1>(nullptr, tkb_b, Ls, acc);
    epi<0>(acc, Ls);
    __syncthreads();

    // ---- phase A2: mask + row softmax from LDS scores -> Pb ----
    {
        short* SC = Ls + L_BST;
        const int* dupr = dup + ((long)(b * 32 + s)) * 512 + lane * 8;
        int4 d0 = *(const int4*)dupr, d1 = *(const int4*)(dupr + 4);
        int dm[8] = {d0.x, d0.y, d0.z, d0.w, d1.x, d1.y, d1.z, d1.w};
        for (int j = 0; j < 8; ++j) {
            int row = w * 8 + j;
            short8 v8 = *(const short8*)(SC + row * 512 + lane * 8);
            const int* adjr = adj + ((long)(b * 64 + row)) * 512 + lane * 8;
            int4 a0 = *(const int4*)adjr, a1 = *(const int4*)(adjr + 4);
            int am[8] = {a0.x, a0.y, a0.z, a0.w, a1.x, a1.y, a1.z, a1.w};
            float v[8];
            float m = -INFINITY;
#pragma unroll
            for (int i = 0; i < 8; ++i) {
                v[i] = (am[i] && !dm[i]) ? b2f(v8[i]) : -INFINITY;
                m = fmaxf(m, v[i]);
            }
#pragma unroll
            for (int d = 32; d >= 1; d >>= 1) m = fmaxf(m, __shfl_xor(m, d));
            float sum = 0.f;
#pragma unroll
            for (int i = 0; i < 8; ++i) {
                float e = (m == -INFINITY) ? 0.f : expf(v[i] - m);
                v[i] = e; sum += e;
            }
#pragma unroll
            for (int d = 32; d >= 1; d >>= 1) sum += __shfl_xor(sum, d);
            float inv = sum > 0.f ? 1.f / sum : 0.f;
            short8 o;
#pragma unroll
            for (int i = 0; i < 8; ++i) o[i] = f2bs(v[i] * inv);
            *(short8*)(Prows + (long)row * 512 + lane * 8) = o;
        }
    }
    __syncthreads();        // drains P stores + frees SC for restaging

    // ---- phase B: gh = tanh(tq @ Wtout2^T + P @ tkWT_b^T) ----
#pragma unroll
    for (int i = 0; i < 4; ++i)
#pragma unroll
        for (int j = 0; j < 4; ++j) { acc[i][j][0]=0.f; acc[i][j][1]=0.f; acc[i][j][2]=0.f; acc[i][j][3]=0.f; }
    tgemmv<1>(nullptr, WT7, Ls, acc);      // B2: uses tq (L_TQ) while it's live
    tgemmv<0>(Prows, tkWT_b, Ls, acc);     // B1: stages P from global
    epi<1>(acc, Ls);                       // tanh -> gh overwrites L_TQ (swizzled)
    __syncthreads();

    // ---- phase C: hk = elu(gh @ Whk^T + b_hk); hs = hk . hq ----
#pragma unroll
    for (int i = 0; i < 4; ++i)
#pragma unroll
        for (int j = 0; j < 4; ++j) { acc[i][j][0]=0.f; acc[i][j][1]=0.f; acc[i][j][2]=0.f; acc[i][j][3]=0.f; }
    tgemmv<1>(nullptr, WT8, Ls, acc);      // A-frags = gh from L_TQ

    float* F     = (float*)(Ls + L_BST);   // f32 scratch over staging region
    float* redf  = F;                      // [8][64]
    float* hal   = F + 512;                // [64]
    float* partf = F + 576;                // [8][512]
    {
        float bv[4], hqv[4];
#pragma unroll
        for (int ni = 0; ni < 4; ++ni) {
            int col = w * 64 + ni * 16 + l16;
            bv[ni]  = b_hk[col];
            hqv[ni] = HQ[col];
        }
#pragma unroll
        for (int mi = 0; mi < 4; ++mi)
#pragma unroll
            for (int r = 0; r < 4; ++r) {
                float p = 0.f;
#pragma unroll
                for (int ni = 0; ni < 4; ++ni)
                    p += eluf(acc[mi][ni][r] + bv[ni]) * hqv[ni];
                p += __shfl_xor(p, 1);
                p += __shfl_xor(p, 2);
                p += __shfl_xor(p, 4);
                p += __shfl_xor(p, 8);
                if (l16 == 0) redf[w * 64 + mi * 16 + quad * 4 + r] = p;
            }
    }
    __syncthreads();

    // ---- head softmax over 64 heads (wave 0) ----
    if (tid < 64) {
        float sv_raw = 0.f;
#pragma unroll
        for (int w2 = 0; w2 < 8; ++w2) sv_raw += redf[w2 * 64 + tid];
        int hv = head[b * 64 + tid];
        unsigned long long ball = __ballot(hv != 0);
        int len = __popcll(ball);
        float sv = (tid < len) ? sv_raw : -INFINITY;
        float m = sv;
#pragma unroll
        for (int d = 32; d >= 1; d >>= 1) m = fmaxf(m, __shfl_xor(m, d));
        float e = expf(sv - m);
        float sum = e;
#pragma unroll
        for (int d = 32; d >= 1; d >>= 1) sum += __shfl_xor(sum, d);
        hal[tid] = e / sum;
    }
    __syncthreads();

    // ---- prob = head_attn . P ----
    {
        const short* tab = Prows + (long)(w * 8) * 512 + lane * 8;
        float a2[8] = {};
#pragma unroll
        for (int k = 0; k < 8; ++k) {
            float a = hal[w * 8 + k];
            short8 tv = *(const short8*)(tab + (long)k * 512);
#pragma unroll
            for (int u = 0; u < 8; ++u) a2[u] += a * b2f(tv[u]);
        }
        float4* pp = (float4*)&partf[w * 512 + lane * 8];
        pp[0] = make_float4(a2[0], a2[1], a2[2], a2[3]);
        pp[1] = make_float4(a2[4], a2[5], a2[6], a2[7]);
    }
    __syncthreads();

    {
        float a = 0.f;
#pragma unroll
        for (int w2 = 0; w2 < 8; ++w2) a += partf[w2 * 512 + tid];
        out[(long)n * 512 + tid] = logf(a + 1e-20f);
    }
}

// ---------------------------------------------------------------------------
// prep (vectorized): float4 casts | 2-rows/block float4 gathers | transposes
// ---------------------------------------------------------------------------
struct WTDesc { const float* src[9]; short* dst[9]; };

__global__ __launch_bounds__(256) void prep(
    const float* __restrict__ dec_out, const float* __restrict__ history,
    short* __restrict__ decb,
    const float* __restrict__ emb, const int* __restrict__ head, const int* __restrict__ tail,
    short* __restrict__ embAll, WTDesc wd)
{
    __shared__ float t[32][33];
    const int id = blockIdx.x, tid = threadIdx.x;
    if (id < 132) {
        int i = (id * 256 + tid) * 4;
        float4 v = (i < 131072) ? *(const float4*)(dec_out + i)
                                : *(const float4*)(history + (i - 131072));
        short4 o;
        o.x = f2bs(v.x); o.y = f2bs(v.y); o.z = f2bs(v.z); o.w = f2bs(v.w);
        *(short4*)(decb + i) = o;
    } else if (id < 132 + 2304) {
        int r = (id - 132) * 2 + (tid >> 7);
        int c4 = (tid & 127) * 4;
        int idx = (r < 512) ? head[r] : tail[r - 512];
        float4 v = *(const float4*)(emb + (long)idx * 512 + c4);
        short4 o;
        o.x = f2bs(v.x); o.y = f2bs(v.y); o.z = f2bs(v.z); o.w = f2bs(v.w);
        *(short4*)(embAll + (long)r * 512 + c4) = o;
    } else {
        int q = id - 2436;
        int z = q >> 8, xy = q & 255;
        int x = xy & 15, y = xy >> 4;
        const float* src = wd.src[z];
        short* dst = wd.dst[z];
        int k0 = y * 32, n0 = x * 32;
        int tx = tid & 31, ty = tid >> 5;
#pragma unroll
        for (int i = 0; i < 32; i += 8)
            t[ty + i][tx] = src[(long)(k0 + ty + i) * 512 + n0 + tx];
        __syncthreads();
#pragma unroll
        for (int i = 0; i < 32; i += 8)
            dst[(long)(n0 + ty + i) * 512 + k0 + tx] = f2bs(t[tx][ty + i]);
    }
}

// ---------------------------------------------------------------------------
// Merged front GEMMs: qall (0-47) | qe (48-63) | tk producers (64-191) |
// tkWT consumers (192-319). Producers signal per-b flags after their tkb
// tile stores drain; consumers spin (co-residency guaranteed: 320 blocks x
// 32KB LDS <= 5 blocks/CU). One release/acquire cache-op per block (r3 rule).
// ---------------------------------------------------------------------------
__global__ __launch_bounds__(256) void mgemm_multi(
    const short* __restrict__ decb, const short* __restrict__ WTall, float* __restrict__ qall,
    const short* __restrict__ embAll, const short* __restrict__ WTe, float* __restrict__ qe,
    const short* __restrict__ WTk, const float* __restrict__ b_tk, short* __restrict__ tkb,
    const short* __restrict__ WTo1, short* __restrict__ tkWTb, unsigned* __restrict__ flags)
{
    __shared__ short Ls[16384];
    int id = blockIdx.x;
    if (id < 48) {
        int y = id >> 4, x = id & 15;
        gcore<0, 0>(decb, WTall, nullptr, qall, 2048, 512, y * 128, x * 128, y * 128, Ls);
    } else if (id < 64) {
        int id2 = id - 48, y = id2 >> 2, x = id2 & 3;
        gcore<0, 0>(embAll, WTe, nullptr, qe, 512, 512, y * 128, x * 128, y * 128, Ls);
    } else if (id < 192) {
        int id3 = id - 64, y = id3 >> 2, x = id3 & 3;
        gcore<1, 1>(embAll, WTk, b_tk, tkb, 512, 512, 512 + y * 128, x * 128, y * 128, Ls);
        // producer: tkb rows [y*128, y*128+128) done -> signal b = y>>2.
        __syncthreads();                     // all waves' stores vmcnt-drained
        if (threadIdx.x == 0)
            __hip_atomic_fetch_add(&flags[(y >> 2) * 16], 1u,
                                   __ATOMIC_RELEASE, __HIP_MEMORY_SCOPE_AGENT);
    } else {
        int id4 = id - 192;                  // [0,128)
        int z = id4 >> 4, r = id4 & 15;
        int x = r & 3, y2 = r >> 2;
        // consumer: wait for all 16 tk producer tiles of b=z.
        if (threadIdx.x == 0) {
            int guard = 0;
            while (__hip_atomic_load(&flags[z * 16], __ATOMIC_RELAXED,
                                     __HIP_MEMORY_SCOPE_AGENT) < 16u) {
                __builtin_amdgcn_s_sleep(8);
                if (++guard > (1 << 22)) break;   // wrong-answer, not hang
            }
            (void)__hip_atomic_load(&flags[z * 16], __ATOMIC_ACQUIRE,
                                    __HIP_MEMORY_SCOPE_AGENT);
        }
        __syncthreads();
        gcore<0, 1>(WTo1, tkb + (long)z * 262144, nullptr,
                    tkWTb + (long)z * 262144, 512, 512, y2 * 128, x * 128, y2 * 128, Ls);
    }
}

extern "C" void kernel_launch(void* const* d_in, const int* in_sizes, int n_in,
                              void* d_out, int out_size, void* d_ws, size_t ws_size,
                              hipStream_t stream)
{
    const float* dec_out = (const float*)d_in[0];
    const float* history = (const float*)d_in[1];
    const int*   head    = (const int*)d_in[2];
    const int*   tail    = (const int*)d_in[3];
    const int*   adj     = (const int*)d_in[4];
    const int*   dup     = (const int*)d_in[5];
    const float* emb     = (const float*)d_in[6];
    const float* W_tq    = (const float*)d_in[7];
    const float* b_tq    = (const float*)d_in[8];
    const float* W_tk    = (const float*)d_in[9];
    const float* b_tk    = (const float*)d_in[10];
    const float* W_tout  = (const float*)d_in[11];
    const float* W_hq    = (const float*)d_in[12];
    const float* b_hq    = (const float*)d_in[13];
    const float* W_hk    = (const float*)d_in[14];
    const float* b_hk    = (const float*)d_in[15];
    float* out = (float*)d_out;

    char* ws = (char*)d_ws;
    auto alloc = [&](size_t bytes) -> void* {
        char* p = ws;
        ws += (bytes + 255) & ~(size_t)255;
        return (void*)p;
    };
    unsigned* flags = (unsigned*)alloc(512);                 // 8 flags, 64B apart
    short* decb   = (short*)alloc((size_t)384 * 512 * 2);    // dec 0..255, hist 256..263
    short* embAll = (short*)alloc((size_t)4608 * 512 * 2);   // head 0..511, tail 512..4607
    short* WT     = (short*)alloc((size_t)9 * 512 * 512 * 2);
    float* qall   = (float*)alloc((size_t)384 * 2048 * 4);   // [qd|hqp|qh'|hq2']
    float* qe     = (float*)alloc((size_t)512 * 512 * 4);
    short* tkb    = (short*)alloc((size_t)4096 * 512 * 2);
    short* tkWTb  = (short*)alloc((size_t)4096 * 512 * 2);
    short* Pb     = (short*)alloc((size_t)16384 * 512 * 2);  // tail_attn

    // WT slab: 0 Wd^T | 1 Whq1^T | 2 Wtq2^T | 3 Whq2^T | 4 We^T | 5 Wtk^T
    //          6 Wtout1^T | 7 Wtout2^T | 8 Whk^T
    WTDesc wd;
    wd.src[0] = W_tq;               wd.dst[0] = WT;
    wd.src[1] = W_hq;               wd.dst[1] = WT + (size_t)1 * 262144;
    wd.src[2] = W_tq + 512 * 512;   wd.dst[2] = WT + (size_t)2 * 262144;
    wd.src[3] = W_hq + 512 * 512;   wd.dst[3] = WT + (size_t)3 * 262144;
    wd.src[4] = W_tq + 1024 * 512;  wd.dst[4] = WT + (size_t)4 * 262144;
    wd.src[5] = W_tk;               wd.dst[5] = WT + (size_t)5 * 262144;
    wd.src[6] = W_tout;             wd.dst[6] = WT + (size_t)6 * 262144;
    wd.src[7] = W_tout + 512 * 512; wd.dst[7] = WT + (size_t)7 * 262144;
    wd.src[8] = W_hk;               wd.dst[8] = WT + (size_t)8 * 262144;

    hipMemsetAsync(flags, 0, 512, stream);
    // 1: casts / gathers / weight transposes
    prep<<<4740, 256, 0, stream>>>(dec_out, history, decb, emb, head, tail, embAll, wd);
    // 2: qall | qe | tk | tkWT (merged, producer->consumer flags)
    mgemm_multi<<<320, 256, 0, stream>>>(decb, WT, qall, embAll, WT + (size_t)4 * 262144, qe,
                                         WT + (size_t)5 * 262144, b_tk, tkb,
                                         WT + (size_t)6 * 262144, tkWTb, flags);
    // 3: fused tail (round-5 structure + T5 setprio)
    tail_kernel<<<256, 512, 0, stream>>>(qall, qe, b_tq, b_hq, tkb, tkWTb, WT,
                                         adj, dup, head, b_hk, Pb, out);
}

// Round 12
// 197.705 us; speedup vs baseline: 1.0408x; 1.0408x over previous
//
#include <hip/hip_runtime.h>
#include <math.h>

#define BB 8
#define SS 32
#define HN 64
#define TN 512
#define HID 512

typedef __attribute__((ext_vector_type(8))) short short8;
typedef __attribute__((ext_vector_type(4))) float f32x4;

__device__ __forceinline__ float eluf(float x) { return x > 0.f ? x : (expf(x) - 1.f); }

__device__ __forceinline__ short f2bs(float f) {
    union { float f; unsigned int u; } v; v.f = f;
    unsigned int r = v.u + 0x7fffu + ((v.u >> 16) & 1u);
    return (short)(r >> 16);
}
__device__ __forceinline__ float b2f(short s) {
    union { unsigned int u; float f; } v;
    v.u = ((unsigned int)(unsigned short)s) << 16;
    return v.f;
}

__device__ __forceinline__ void gld16(const void* g, void* l) {
    __builtin_amdgcn_global_load_lds(
        (const __attribute__((address_space(1))) void*)g,
        (__attribute__((address_space(3))) void*)l, 16, 0, 0);
}

// ---------------------------------------------------------------------------
// 4-wave 128x128 GEMM core, BK=64: front-side GEMMs (qall/qe/tk/tkWT).
// Ls = 16384 shorts (32KB). OUTB: 0=f32, 1=bf16.  (verified baseline core)
// ---------------------------------------------------------------------------
template <int ACT, int OUTB>
__device__ __forceinline__ void gcore(
    const short* __restrict__ A, const short* __restrict__ B,
    const float* __restrict__ bias, void* __restrict__ Cv,
    int ldc, int K, int m0, int n0, int cm0, short* Ls)
{
    short* Al = Ls;
    short* Bl = Ls + 8192;
    const int tid  = threadIdx.x;
    const int lane = tid & 63;
    const int w    = tid >> 6;
    const int wr   = w >> 1, wc = w & 1;
    const int l16  = lane & 15, quad = lane >> 4;

    const int srow = w * 16 + (lane >> 2);
    const int scol = (lane & 3) * 8;

    f32x4 acc[4][4];
#pragma unroll
    for (int i = 0; i < 4; ++i)
#pragma unroll
        for (int j = 0; j < 4; ++j) { acc[i][j][0]=0.f; acc[i][j][1]=0.f; acc[i][j][2]=0.f; acc[i][j][3]=0.f; }

    short* lA = Al + w * 512;
    short* lB = Bl + w * 512;
    const long rstep = (long)64 * K;

    const short* Ag = A + (long)(m0 + srow) * K + scol;
    const short* Bg = B + (long)(n0 + srow) * K + scol;
    for (int kt = 0; kt < K; kt += 64) {
        __syncthreads();
        gld16(Ag + kt, lA);
        gld16(Ag + kt + rstep, lA + 2048);
        gld16(Ag + kt + 32, lA + 4096);
        gld16(Ag + kt + 32 + rstep, lA + 4096 + 2048);
        gld16(Bg + kt, lB);
        gld16(Bg + kt + rstep, lB + 2048);
        gld16(Bg + kt + 32, lB + 4096);
        gld16(Bg + kt + 32 + rstep, lB + 4096 + 2048);
        __syncthreads();
#pragma unroll
        for (int h = 0; h < 2; ++h) {
            short8 af[4], bf4[4];
#pragma unroll
            for (int mi = 0; mi < 4; ++mi)
                af[mi] = *(const short8*)(Al + h * 4096 + (wr * 64 + mi * 16 + l16) * 32 + quad * 8);
#pragma unroll
            for (int ni = 0; ni < 4; ++ni)
                bf4[ni] = *(const short8*)(Bl + h * 4096 + (wc * 64 + ni * 16 + l16) * 32 + quad * 8);
#pragma unroll
            for (int mi = 0; mi < 4; ++mi)
#pragma unroll
                for (int ni = 0; ni < 4; ++ni)
                    acc[mi][ni] = __builtin_amdgcn_mfma_f32_16x16x32_bf16(af[mi], bf4[ni], acc[mi][ni], 0, 0, 0);
        }
    }

    __syncthreads();

    float bv[4];
#pragma unroll
    for (int ni = 0; ni < 4; ++ni)
        bv[ni] = bias ? bias[n0 + wc * 64 + ni * 16 + l16] : 0.f;

    if (OUTB == 1) {
        short* eb = Ls + w * 1152;
        const int er = lane >> 2;
        const int ec = (lane & 3) * 16;
#pragma unroll
        for (int mi = 0; mi < 4; ++mi) {
#pragma unroll
            for (int ni = 0; ni < 4; ++ni)
#pragma unroll
                for (int r = 0; r < 4; ++r) {
                    float x = acc[mi][ni][r] + bv[ni];
                    if (ACT == 1) x = eluf(x);
                    eb[(quad * 4 + r) * 72 + ni * 16 + l16] = f2bs(x);
                }
            __builtin_amdgcn_sched_barrier(0);
            short8 v0 = *(const short8*)&eb[er * 72 + ec];
            short8 v1 = *(const short8*)&eb[er * 72 + ec + 8];
            long cb = (long)(cm0 + wr * 64 + mi * 16 + er) * ldc + n0 + wc * 64 + ec;
            *(short8*)((short*)Cv + cb)     = v0;
            *(short8*)((short*)Cv + cb + 8) = v1;
            __builtin_amdgcn_sched_barrier(0);
        }
    } else {
#pragma unroll
        for (int mi = 0; mi < 4; ++mi)
#pragma unroll
            for (int ni = 0; ni < 4; ++ni) {
                int gc = n0 + wc * 64 + ni * 16 + l16;
#pragma unroll
                for (int r = 0; r < 4; ++r) {
                    float x = acc[mi][ni][r] + bv[ni];
                    if (ACT == 1) x = eluf(x);
                    ((float*)Cv)[(long)(cm0 + wr * 64 + mi * 16 + quad * 4 + r) * ldc + gc] = x;
                }
            }
    }
}

// ---------------------------------------------------------------------------
// Tail LDS layout (shorts). Total 79872 shorts = 156 KB (<160 KB/CU, 1 blk/CU).
//  L_TQ : tq rows (granule-XOR swizzled), later gh rows
//  L_BST: B staging double-buffer; also scores scratch / f32 scratch
//  L_AST: A staging double-buffer (P panel)
//  L_EB : epilogue transpose buffers
//  L_HQ : hq f32[512]
// ---------------------------------------------------------------------------
#define L_TQ   0
#define L_BST  32768
#define L_AST  65536
#define L_EB   69632
#define L_HQ   78848
#define L_TOT  79872

// ---------------------------------------------------------------------------
// Tail GEMM: C[64][512] += A[64][512] @ B[512][512]^T, BK=32, double-buffered
// staging with counted vmcnt (T3/T4), granule-XOR swizzled LDS (T2).
// AFT=1: A-fragments from persistent swizzled L_TQ (no A staging).
// AFT=0: A staged from global (P panel).
// ---------------------------------------------------------------------------
template <int AFT>
__device__ __forceinline__ void tgemmv(
    const short* __restrict__ Arows, const short* __restrict__ B,
    short* Ls, f32x4 (&acc)[4][4])
{
    const int tid  = threadIdx.x;
    const int lane = tid & 63;
    const int w    = tid >> 6;
    const int l16  = lane & 15, quad = lane >> 4;
    short* TQ  = Ls + L_TQ;
    short* BST = Ls + L_BST;
    short* AST = Ls + L_AST;

    auto STAGE = [&](int kt, int p) {
        short* Bl = BST + p * 16384;
#pragma unroll
        for (int j = 0; j < 4; ++j) {
            int lin = j * 512 + tid;
            int r = lin >> 2, gs = lin & 3;
            int g = gs ^ ((r >> 1) & 3);               // source-permuted granule
            gld16(B + (long)r * 512 + kt + g * 8, Bl + j * 4096 + w * 512);
        }
        if constexpr (AFT == 0) {
            if (tid < 256) {
                short* Al = AST + p * 2048;
                int r = tid >> 2, gs = tid & 3;
                int g = gs ^ ((r >> 1) & 3);
                gld16(Arows + (long)r * 512 + kt + g * 8, Al + w * 512);
            }
        }
    };

    STAGE(0, 0);
    int p = 0;
    for (int kt = 0; kt < 512; kt += 32, p ^= 1) {
        if (kt + 32 < 512) {
            STAGE(kt + 32, p ^ 1);
            if (AFT == 0 && w < 4) asm volatile("s_waitcnt vmcnt(5)" ::: "memory");
            else                   asm volatile("s_waitcnt vmcnt(4)" ::: "memory");
        } else {
            asm volatile("s_waitcnt vmcnt(0)" ::: "memory");
        }
        __builtin_amdgcn_s_barrier();
        __builtin_amdgcn_sched_barrier(0);

        short* Bl = BST + p * 16384;
        short8 af[4], bf[4];
#pragma unroll
        for (int mi = 0; mi < 4; ++mi) {
            int row = mi * 16 + l16;
            if constexpr (AFT == 1) {
                int slot = ((kt >> 3) + quad) ^ (row & 7);
                af[mi] = *(const short8*)(TQ + row * 512 + slot * 8);
            } else {
                short* Al = AST + p * 2048;
                int slot = quad ^ ((row >> 1) & 3);
                af[mi] = *(const short8*)(Al + row * 32 + slot * 8);
            }
        }
#pragma unroll
        for (int ni = 0; ni < 4; ++ni) {
            int row = w * 64 + ni * 16 + l16;
            int slot = quad ^ ((row >> 1) & 3);
            bf[ni] = *(const short8*)(Bl + row * 32 + slot * 8);
        }
#pragma unroll
        for (int mi = 0; mi < 4; ++mi)
#pragma unroll
            for (int ni = 0; ni < 4; ++ni)
                acc[mi][ni] = __builtin_amdgcn_mfma_f32_16x16x32_bf16(af[mi], bf[ni], acc[mi][ni], 0, 0, 0);
        asm volatile("s_waitcnt lgkmcnt(0)" ::: "memory");
        __builtin_amdgcn_s_barrier();
        __builtin_amdgcn_sched_barrier(0);
    }
}

// Epilogue: wave tile 64x64 -> bf16 rows via eb transpose (verified pattern).
// MODE 0: scores -> L_BST linear [64][512].  MODE 1: tanh -> L_TQ swizzled.
template <int MODE>
__device__ __forceinline__ void epi(f32x4 (&acc)[4][4], short* Ls)
{
    const int tid  = threadIdx.x;
    const int lane = tid & 63;
    const int w    = tid >> 6;
    const int l16  = lane & 15, quad = lane >> 4;
    short* eb = Ls + L_EB + w * 1152;
    const int er = lane >> 2;
    const int ec = (lane & 3) * 16;
#pragma unroll
    for (int mi = 0; mi < 4; ++mi) {
#pragma unroll
        for (int ni = 0; ni < 4; ++ni)
#pragma unroll
            for (int r = 0; r < 4; ++r) {
                float x = acc[mi][ni][r];
                if (MODE == 1) x = tanhf(x);
                eb[(quad * 4 + r) * 72 + ni * 16 + l16] = f2bs(x);
            }
        __builtin_amdgcn_sched_barrier(0);
        short8 v0 = *(const short8*)&eb[er * 72 + ec];
        short8 v1 = *(const short8*)&eb[er * 72 + ec + 8];
        int row = mi * 16 + er;
        if (MODE == 0) {
            short* SC = Ls + L_BST;
            *(short8*)(SC + row * 512 + w * 64 + ec)     = v0;
            *(short8*)(SC + row * 512 + w * 64 + ec + 8) = v1;
        } else {
            int g0 = (w * 64 + ec) >> 3;
            *(short8*)(Ls + L_TQ + row * 512 + ((g0)     ^ (row & 7)) * 8) = v0;
            *(short8*)(Ls + L_TQ + row * 512 + ((g0 + 1) ^ (row & 7)) * 8) = v1;
        }
        __builtin_amdgcn_sched_barrier(0);
    }
}

// ---------------------------------------------------------------------------
// Tail: one block per n=(b,s). Builds tq/hq in LDS (kills l3's 8192-block
// pass + tqb), then scores -> softmax -> gh -> hk.hq -> head softmax -> prob.
// ---------------------------------------------------------------------------
__global__ __launch_bounds__(512, 1) void tail_kernel(
    const float* __restrict__ qall, const float* __restrict__ qe,
    const float* __restrict__ b_tq, const float* __restrict__ b_hq,
    const short* __restrict__ tkb, const short* __restrict__ tkWTb,
    const short* __restrict__ WT,
    const int* __restrict__ adj, const int* __restrict__ dup,
    const int* __restrict__ head, const float* __restrict__ b_hk,
    short* __restrict__ Pb, float* __restrict__ out)
{
    __shared__ short Ls[L_TOT];
    const int tid  = threadIdx.x;
    const int lane = tid & 63;
    const int w    = tid >> 6;
    const int l16  = lane & 15, quad = lane >> 4;

    // XCD swizzle: all 32 blocks of one b land on one XCD (round-robin bid%8).
    const int n = (blockIdx.x & 7) * 32 + (blockIdx.x >> 3);
    const int b = n >> 5;
    const int s = n & 31;
    const long rb = (long)n * 64;

    const short* tkb_b  = tkb + (long)b * 262144;
    const short* tkWT_b = tkWTb + (long)b * 262144;
    const short* WT7    = WT + (size_t)7 * 262144;
    const short* WT8    = WT + (size_t)8 * 262144;
    short* Prows = Pb + rb * 512;
    float* HQ = (float*)(Ls + L_HQ);

    // ---- phase 0: build tq rows (swizzled into L_TQ) + hq vector ----
    {
        const int cg = tid & 63;            // col granule
        const int wg = tid >> 6;            // row group (8 rows per wave)
        float4 qd0 = *(const float4*)(qall + (long)n * 2048 + cg * 8);
        float4 qd1 = *(const float4*)(qall + (long)n * 2048 + cg * 8 + 4);
        float4 qh0 = *(const float4*)(qall + (long)(256 + b) * 2048 + 1024 + cg * 8);
        float4 qh1 = *(const float4*)(qall + (long)(256 + b) * 2048 + 1024 + cg * 8 + 4);
        float4 bt0 = *(const float4*)(b_tq + cg * 8);
        float4 bt1 = *(const float4*)(b_tq + cg * 8 + 4);
        float base[8] = {qd0.x + qh0.x + bt0.x, qd0.y + qh0.y + bt0.y,
                         qd0.z + qh0.z + bt0.z, qd0.w + qh0.w + bt0.w,
                         qd1.x + qh1.x + bt1.x, qd1.y + qh1.y + bt1.y,
                         qd1.z + qh1.z + bt1.z, qd1.w + qh1.w + bt1.w};
#pragma unroll
        for (int i = 0; i < 8; ++i) {
            int h = wg * 8 + i;
            const float* er = qe + (long)(b * 64 + h) * 512 + cg * 8;
            float4 e0 = *(const float4*)er;
            float4 e1 = *(const float4*)(er + 4);
            float ev[8] = {e0.x, e0.y, e0.z, e0.w, e1.x, e1.y, e1.z, e1.w};
            short8 o;
#pragma unroll
            for (int u = 0; u < 8; ++u) o[u] = f2bs(eluf(base[u] + ev[u]));
            int slot = cg ^ (h & 7);
            *(short8*)(Ls + L_TQ + h * 512 + slot * 8) = o;
        }
        if (tid < 512) {
            HQ[tid] = eluf(qall[(long)n * 2048 + 512 + tid]
                         + qall[(long)(256 + b) * 2048 + 1536 + tid] + b_hq[tid]);
        }
    }
    __syncthreads();

    f32x4 acc[4][4];
#pragma unroll
    for (int i = 0; i < 4; ++i)
#pragma unroll
        for (int j = 0; j < 4; ++j) { acc[i][j][0]=0.f; acc[i][j][1]=0.f; acc[i][j][2]=0.f; acc[i][j][3]=0.f; }

    // ---- phase A: scores = tq @ tk_b^T -> L_BST linear ----
    tgemmv<1>(nullptr, tkb_b, Ls, acc);
    epi<0>(acc, Ls);
    __syncthreads();

    // ---- phase A2: mask + row softmax from LDS scores -> Pb ----
    {
        short* SC = Ls + L_BST;
        const int* dupr = dup + ((long)(b * 32 + s)) * 512 + lane * 8;
        int4 d0 = *(const int4*)dupr, d1 = *(const int4*)(dupr + 4);
        int dm[8] = {d0.x, d0.y, d0.z, d0.w, d1.x, d1.y, d1.z, d1.w};
        for (int j = 0; j < 8; ++j) {
            int row = w * 8 + j;
            short8 v8 = *(const short8*)(SC + row * 512 + lane * 8);
            const int* adjr = adj + ((long)(b * 64 + row)) * 512 + lane * 8;
            int4 a0 = *(const int4*)adjr, a1 = *(const int4*)(adjr + 4);
            int am[8] = {a0.x, a0.y, a0.z, a0.w, a1.x, a1.y, a1.z, a1.w};
            float v[8];
            float m = -INFINITY;
#pragma unroll
            for (int i = 0; i < 8; ++i) {
                v[i] = (am[i] && !dm[i]) ? b2f(v8[i]) : -INFINITY;
                m = fmaxf(m, v[i]);
            }
#pragma unroll
            for (int d = 32; d >= 1; d >>= 1) m = fmaxf(m, __shfl_xor(m, d));
            float sum = 0.f;
#pragma unroll
            for (int i = 0; i < 8; ++i) {
                float e = (m == -INFINITY) ? 0.f : expf(v[i] - m);
                v[i] = e; sum += e;
            }
#pragma unroll
            for (int d = 32; d >= 1; d >>= 1) sum += __shfl_xor(sum, d);
            float inv = sum > 0.f ? 1.f / sum : 0.f;
            short8 o;
#pragma unroll
            for (int i = 0; i < 8; ++i) o[i] = f2bs(v[i] * inv);
            *(short8*)(Prows + (long)row * 512 + lane * 8) = o;
        }
    }
    __syncthreads();        // drains P stores (vmcnt in barrier) + frees SC

    // ---- phase B: gh = tanh(tq @ Wtout2^T + P @ tkWT_b^T) ----
#pragma unroll
    for (int i = 0; i < 4; ++i)
#pragma unroll
        for (int j = 0; j < 4; ++j) { acc[i][j][0]=0.f; acc[i][j][1]=0.f; acc[i][j][2]=0.f; acc[i][j][3]=0.f; }
    tgemmv<1>(nullptr, WT7, Ls, acc);      // B2: uses tq (L_TQ) while it's live
    tgemmv<0>(Prows, tkWT_b, Ls, acc);     // B1: stages P from global
    epi<1>(acc, Ls);                       // tanh -> gh overwrites L_TQ (swizzled)
    __syncthreads();

    // ---- phase C: hk = elu(gh @ Whk^T + b_hk); hs = hk . hq ----
#pragma unroll
    for (int i = 0; i < 4; ++i)
#pragma unroll
        for (int j = 0; j < 4; ++j) { acc[i][j][0]=0.f; acc[i][j][1]=0.f; acc[i][j][2]=0.f; acc[i][j][3]=0.f; }
    tgemmv<1>(nullptr, WT8, Ls, acc);      // A-frags = gh from L_TQ

    float* F     = (float*)(Ls + L_BST);   // f32 scratch over staging region
    float* redf  = F;                      // [8][64]
    float* hal   = F + 512;                // [64]
    float* partf = F + 576;                // [8][512]
    {
        float bv[4], hqv[4];
#pragma unroll
        for (int ni = 0; ni < 4; ++ni) {
            int col = w * 64 + ni * 16 + l16;
            bv[ni]  = b_hk[col];
            hqv[ni] = HQ[col];
        }
#pragma unroll
        for (int mi = 0; mi < 4; ++mi)
#pragma unroll
            for (int r = 0; r < 4; ++r) {
                float p = 0.f;
#pragma unroll
                for (int ni = 0; ni < 4; ++ni)
                    p += eluf(acc[mi][ni][r] + bv[ni]) * hqv[ni];
                p += __shfl_xor(p, 1);
                p += __shfl_xor(p, 2);
                p += __shfl_xor(p, 4);
                p += __shfl_xor(p, 8);
                if (l16 == 0) redf[w * 64 + mi * 16 + quad * 4 + r] = p;
            }
    }
    __syncthreads();

    // ---- head softmax over 64 heads (wave 0) ----
    if (tid < 64) {
        float sv_raw = 0.f;
#pragma unroll
        for (int w2 = 0; w2 < 8; ++w2) sv_raw += redf[w2 * 64 + tid];
        int hv = head[b * 64 + tid];
        unsigned long long ball = __ballot(hv != 0);
        int len = __popcll(ball);
        float sv = (tid < len) ? sv_raw : -INFINITY;
        float m = sv;
#pragma unroll
        for (int d = 32; d >= 1; d >>= 1) m = fmaxf(m, __shfl_xor(m, d));
        float e = expf(sv - m);
        float sum = e;
#pragma unroll
        for (int d = 32; d >= 1; d >>= 1) sum += __shfl_xor(sum, d);
        hal[tid] = e / sum;
    }
    __syncthreads();

    // ---- prob = head_attn . P ----
    {
        const short* tab = Prows + (long)(w * 8) * 512 + lane * 8;
        float a2[8] = {};
#pragma unroll
        for (int k = 0; k < 8; ++k) {
            float a = hal[w * 8 + k];
            short8 tv = *(const short8*)(tab + (long)k * 512);
#pragma unroll
            for (int u = 0; u < 8; ++u) a2[u] += a * b2f(tv[u]);
        }
        float4* pp = (float4*)&partf[w * 512 + lane * 8];
        pp[0] = make_float4(a2[0], a2[1], a2[2], a2[3]);
        pp[1] = make_float4(a2[4], a2[5], a2[6], a2[7]);
    }
    __syncthreads();

    {
        float a = 0.f;
#pragma unroll
        for (int w2 = 0; w2 < 8; ++w2) a += partf[w2 * 512 + tid];
        out[(long)n * 512 + tid] = logf(a + 1e-20f);
    }
}

// ---------------------------------------------------------------------------
// prep (vectorized): float4 casts | 2-rows/block float4 gathers | transposes
// ---------------------------------------------------------------------------
struct WTDesc { const float* src[9]; short* dst[9]; };

__global__ __launch_bounds__(256) void prep(
    const float* __restrict__ dec_out, const float* __restrict__ history,
    short* __restrict__ decb,
    const float* __restrict__ emb, const int* __restrict__ head, const int* __restrict__ tail,
    short* __restrict__ embAll, WTDesc wd)
{
    __shared__ float t[32][33];
    const int id = blockIdx.x, tid = threadIdx.x;
    if (id < 132) {
        int i = (id * 256 + tid) * 4;
        float4 v = (i < 131072) ? *(const float4*)(dec_out + i)
                                : *(const float4*)(history + (i - 131072));
        short4 o;
        o.x = f2bs(v.x); o.y = f2bs(v.y); o.z = f2bs(v.z); o.w = f2bs(v.w);
        *(short4*)(decb + i) = o;
    } else if (id < 132 + 2304) {
        int r = (id - 132) * 2 + (tid >> 7);
        int c4 = (tid & 127) * 4;
        int idx = (r < 512) ? head[r] : tail[r - 512];
        float4 v = *(const float4*)(emb + (long)idx * 512 + c4);
        short4 o;
        o.x = f2bs(v.x); o.y = f2bs(v.y); o.z = f2bs(v.z); o.w = f2bs(v.w);
        *(short4*)(embAll + (long)r * 512 + c4) = o;
    } else {
        int q = id - 2436;
        int z = q >> 8, xy = q & 255;
        int x = xy & 15, y = xy >> 4;
        const float* src = wd.src[z];
        short* dst = wd.dst[z];
        int k0 = y * 32, n0 = x * 32;
        int tx = tid & 31, ty = tid >> 5;
#pragma unroll
        for (int i = 0; i < 32; i += 8)
            t[ty + i][tx] = src[(long)(k0 + ty + i) * 512 + n0 + tx];
        __syncthreads();
#pragma unroll
        for (int i = 0; i < 32; i += 8)
            dst[(long)(n0 + ty + i) * 512 + k0 + tx] = f2bs(t[tx][ty + i]);
    }
}

// qall (48) | qe (16) | tk (128) in one launch (BK=64 core)
__global__ __launch_bounds__(256) void mgemm_multi(
    const short* __restrict__ decb, const short* __restrict__ WTall, float* __restrict__ qall,
    const short* __restrict__ embAll, const short* __restrict__ WTe, float* __restrict__ qe,
    const short* __restrict__ WTk, const float* __restrict__ b_tk, short* __restrict__ tkb)
{
    __shared__ short Ls[16384];
    int id = blockIdx.x;
    if (id < 48) {
        int y = id >> 4, x = id & 15;
        gcore<0, 0>(decb, WTall, nullptr, qall, 2048, 512, y * 128, x * 128, y * 128, Ls);
    } else if (id < 64) {
        int id2 = id - 48, y = id2 >> 2, x = id2 & 3;
        gcore<0, 0>(embAll, WTe, nullptr, qe, 512, 512, y * 128, x * 128, y * 128, Ls);
    } else {
        int id3 = id - 64, y = id3 >> 2, x = id3 & 3;
        gcore<1, 1>(embAll, WTk, b_tk, tkb, 512, 512, 512 + y * 128, x * 128, y * 128, Ls);
    }
}

// tkWT = Wtout1^T @ tk^T per b (128 blocks)
__global__ __launch_bounds__(256) void tkwt_kernel(
    const short* __restrict__ WTo1, const short* __restrict__ tkb, short* __restrict__ tkWTb)
{
    __shared__ short Ls[16384];
    int id = blockIdx.x;
    int z = id >> 4, r = id & 15;
    int x = r & 3, y = r >> 2;
    gcore<0, 1>(WTo1, tkb + (long)z * 262144, nullptr,
                tkWTb + (long)z * 262144, 512, 512, y * 128, x * 128, y * 128, Ls);
}

extern "C" void kernel_launch(void* const* d_in, const int* in_sizes, int n_in,
                              void* d_out, int out_size, void* d_ws, size_t ws_size,
                              hipStream_t stream)
{
    const float* dec_out = (const float*)d_in[0];
    const float* history = (const float*)d_in[1];
    const int*   head    = (const int*)d_in[2];
    const int*   tail    = (const int*)d_in[3];
    const int*   adj     = (const int*)d_in[4];
    const int*   dup     = (const int*)d_in[5];
    const float* emb     = (const float*)d_in[6];
    const float* W_tq    = (const float*)d_in[7];
    const float* b_tq    = (const float*)d_in[8];
    const float* W_tk    = (const float*)d_in[9];
    const float* b_tk    = (const float*)d_in[10];
    const float* W_tout  = (const float*)d_in[11];
    const float* W_hq    = (const float*)d_in[12];
    const float* b_hq    = (const float*)d_in[13];
    const float* W_hk    = (const float*)d_in[14];
    const float* b_hk    = (const float*)d_in[15];
    float* out = (float*)d_out;

    char* ws = (char*)d_ws;
    auto alloc = [&](size_t bytes) -> void* {
        char* p = ws;
        ws += (bytes + 255) & ~(size_t)255;
        return (void*)p;
    };
    short* decb   = (short*)alloc((size_t)384 * 512 * 2);    // dec 0..255, hist 256..263
    short* embAll = (short*)alloc((size_t)4608 * 512 * 2);   // head 0..511, tail 512..4607
    short* WT     = (short*)alloc((size_t)9 * 512 * 512 * 2);
    float* qall   = (float*)alloc((size_t)384 * 2048 * 4);   // [qd|hqp|qh'|hq2']
    float* qe     = (float*)alloc((size_t)512 * 512 * 4);
    short* tkb    = (short*)alloc((size_t)4096 * 512 * 2);
    short* tkWTb  = (short*)alloc((size_t)4096 * 512 * 2);
    short* Pb     = (short*)alloc((size_t)16384 * 512 * 2);  // tail_attn

    // WT slab: 0 Wd^T | 1 Whq1^T | 2 Wtq2^T | 3 Whq2^T | 4 We^T | 5 Wtk^T
    //          6 Wtout1^T | 7 Wtout2^T | 8 Whk^T
    WTDesc wd;
    wd.src[0] = W_tq;               wd.dst[0] = WT;
    wd.src[1] = W_hq;               wd.dst[1] = WT + (size_t)1 * 262144;
    wd.src[2] = W_tq + 512 * 512;   wd.dst[2] = WT + (size_t)2 * 262144;
    wd.src[3] = W_hq + 512 * 512;   wd.dst[3] = WT + (size_t)3 * 262144;
    wd.src[4] = W_tq + 1024 * 512;  wd.dst[4] = WT + (size_t)4 * 262144;
    wd.src[5] = W_tk;               wd.dst[5] = WT + (size_t)5 * 262144;
    wd.src[6] = W_tout;             wd.dst[6] = WT + (size_t)6 * 262144;
    wd.src[7] = W_tout + 512 * 512; wd.dst[7] = WT + (size_t)7 * 262144;
    wd.src[8] = W_hk;               wd.dst[8] = WT + (size_t)8 * 262144;

    // 1: casts / gathers / weight transposes
    prep<<<4740, 256, 0, stream>>>(dec_out, history, decb, emb, head, tail, embAll, wd);
    // 2: qall | qe | tk
    mgemm_multi<<<192, 256, 0, stream>>>(decb, WT, qall, embAll, WT + (size_t)4 * 262144, qe,
                                         WT + (size_t)5 * 262144, b_tk, tkb);
    // 3: tkWT only (tq/hq builds live in the tail)
    tkwt_kernel<<<128, 256, 0, stream>>>(WT + (size_t)6 * 262144, tkb, tkWTb);
    // 4: fused tail (round-5 structure — session best, 199.95 us)
    tail_kernel<<<256, 512, 0, stream>>>(qall, qe, b_tq, b_hq, tkb, tkWTb, WT,
                                         adj, dup, head, b_hk, Pb, out);
}

// Round 13
// 194.254 us; speedup vs baseline: 1.0593x; 1.0178x over previous
//
#include <hip/hip_runtime.h>
#include <math.h>

#define BB 8
#define SS 32
#define HN 64
#define TN 512
#define HID 512

typedef __attribute__((ext_vector_type(8))) short short8;
typedef __attribute__((ext_vector_type(4))) float f32x4;

__device__ __forceinline__ float eluf(float x) { return x > 0.f ? x : (expf(x) - 1.f); }

__device__ __forceinline__ short f2bs(float f) {
    union { float f; unsigned int u; } v; v.f = f;
    unsigned int r = v.u + 0x7fffu + ((v.u >> 16) & 1u);
    return (short)(r >> 16);
}
__device__ __forceinline__ float b2f(short s) {
    union { unsigned int u; float f; } v;
    v.u = ((unsigned int)(unsigned short)s) << 16;
    return v.f;
}

__device__ __forceinline__ void gld16(const void* g, void* l) {
    __builtin_amdgcn_global_load_lds(
        (const __attribute__((address_space(1))) void*)g,
        (__attribute__((address_space(3))) void*)l, 16, 0, 0);
}

// ---------------------------------------------------------------------------
// 4-wave 128x128 GEMM core, BK=64: front-side GEMMs (qall/qe/tk/tkWT).
// Ls = 16384 shorts (32KB). OUTB: 0=f32, 1=bf16.  (verified baseline core)
// ---------------------------------------------------------------------------
template <int ACT, int OUTB>
__device__ __forceinline__ void gcore(
    const short* __restrict__ A, const short* __restrict__ B,
    const float* __restrict__ bias, void* __restrict__ Cv,
    int ldc, int K, int m0, int n0, int cm0, short* Ls)
{
    short* Al = Ls;
    short* Bl = Ls + 8192;
    const int tid  = threadIdx.x;
    const int lane = tid & 63;
    const int w    = tid >> 6;
    const int wr   = w >> 1, wc = w & 1;
    const int l16  = lane & 15, quad = lane >> 4;

    const int srow = w * 16 + (lane >> 2);
    const int scol = (lane & 3) * 8;

    f32x4 acc[4][4];
#pragma unroll
    for (int i = 0; i < 4; ++i)
#pragma unroll
        for (int j = 0; j < 4; ++j) { acc[i][j][0]=0.f; acc[i][j][1]=0.f; acc[i][j][2]=0.f; acc[i][j][3]=0.f; }

    short* lA = Al + w * 512;
    short* lB = Bl + w * 512;
    const long rstep = (long)64 * K;

    const short* Ag = A + (long)(m0 + srow) * K + scol;
    const short* Bg = B + (long)(n0 + srow) * K + scol;
    for (int kt = 0; kt < K; kt += 64) {
        __syncthreads();
        gld16(Ag + kt, lA);
        gld16(Ag + kt + rstep, lA + 2048);
        gld16(Ag + kt + 32, lA + 4096);
        gld16(Ag + kt + 32 + rstep, lA + 4096 + 2048);
        gld16(Bg + kt, lB);
        gld16(Bg + kt + rstep, lB + 2048);
        gld16(Bg + kt + 32, lB + 4096);
        gld16(Bg + kt + 32 + rstep, lB + 4096 + 2048);
        __syncthreads();
#pragma unroll
        for (int h = 0; h < 2; ++h) {
            short8 af[4], bf4[4];
#pragma unroll
            for (int mi = 0; mi < 4; ++mi)
                af[mi] = *(const short8*)(Al + h * 4096 + (wr * 64 + mi * 16 + l16) * 32 + quad * 8);
#pragma unroll
            for (int ni = 0; ni < 4; ++ni)
                bf4[ni] = *(const short8*)(Bl + h * 4096 + (wc * 64 + ni * 16 + l16) * 32 + quad * 8);
#pragma unroll
            for (int mi = 0; mi < 4; ++mi)
#pragma unroll
                for (int ni = 0; ni < 4; ++ni)
                    acc[mi][ni] = __builtin_amdgcn_mfma_f32_16x16x32_bf16(af[mi], bf4[ni], acc[mi][ni], 0, 0, 0);
        }
    }

    __syncthreads();

    float bv[4];
#pragma unroll
    for (int ni = 0; ni < 4; ++ni)
        bv[ni] = bias ? bias[n0 + wc * 64 + ni * 16 + l16] : 0.f;

    if (OUTB == 1) {
        short* eb = Ls + w * 1152;
        const int er = lane >> 2;
        const int ec = (lane & 3) * 16;
#pragma unroll
        for (int mi = 0; mi < 4; ++mi) {
#pragma unroll
            for (int ni = 0; ni < 4; ++ni)
#pragma unroll
                for (int r = 0; r < 4; ++r) {
                    float x = acc[mi][ni][r] + bv[ni];
                    if (ACT == 1) x = eluf(x);
                    eb[(quad * 4 + r) * 72 + ni * 16 + l16] = f2bs(x);
                }
            __builtin_amdgcn_sched_barrier(0);
            short8 v0 = *(const short8*)&eb[er * 72 + ec];
            short8 v1 = *(const short8*)&eb[er * 72 + ec + 8];
            long cb = (long)(cm0 + wr * 64 + mi * 16 + er) * ldc + n0 + wc * 64 + ec;
            *(short8*)((short*)Cv + cb)     = v0;
            *(short8*)((short*)Cv + cb + 8) = v1;
            __builtin_amdgcn_sched_barrier(0);
        }
    } else {
#pragma unroll
        for (int mi = 0; mi < 4; ++mi)
#pragma unroll
            for (int ni = 0; ni < 4; ++ni) {
                int gc = n0 + wc * 64 + ni * 16 + l16;
#pragma unroll
                for (int r = 0; r < 4; ++r) {
                    float x = acc[mi][ni][r] + bv[ni];
                    if (ACT == 1) x = eluf(x);
                    ((float*)Cv)[(long)(cm0 + wr * 64 + mi * 16 + quad * 4 + r) * ldc + gc] = x;
                }
            }
    }
}

// ---------------------------------------------------------------------------
// Tail LDS layout (shorts). Total 79872 shorts = 156 KB (<160 KB/CU, 1 blk/CU).
//  L_TQ : tq rows (granule-XOR swizzled), later gh rows
//  L_BST: B staging double-buffer; also scores scratch / f32 scratch
//  L_AST: A staging double-buffer (P panel)
//  L_EB : epilogue transpose buffers
//  L_HQ : hq f32[512]
// ---------------------------------------------------------------------------
#define L_TQ   0
#define L_BST  32768
#define L_AST  65536
#define L_EB   69632
#define L_HQ   78848
#define L_TOT  79872

// ---------------------------------------------------------------------------
// Barrier-free tail GEMM (A from persistent swizzled L_TQ): wave-PRIVATE
// B staging. Wave w consumes only B rows [w*64, w*64+64), so it stages its
// own 64x32 slab (4 gld16/step) and syncs with s_waitcnt only — no s_barrier
// in the K-loop. Caller must __syncthreads() after the call before any
// shared write to L_BST.
// ---------------------------------------------------------------------------
__device__ __forceinline__ void tgemmw(
    const short* TQ, const short* __restrict__ B, short* Ls, f32x4 (&acc)[4][4])
{
    const int tid  = threadIdx.x;
    const int lane = tid & 63;
    const int w    = tid >> 6;
    const int l16  = lane & 15, quad = lane >> 4;
    short* BW = Ls + L_BST + w * 2048;     // wave slab base (per buffer +p*16384)

    auto STAGE = [&](int kt, int p) {
        short* dst = BW + p * 16384;
#pragma unroll
        for (int j = 0; j < 4; ++j)
            gld16(B + (long)(w * 64 + j * 16 + (lane >> 2)) * 512 + kt + (lane & 3) * 8,
                  dst + j * 512);
    };

    STAGE(0, 0);
    int p = 0;
    for (int kt = 0; kt < 512; kt += 32, p ^= 1) {
        // my reads of buffer p^1 (prev step) must drain before overwriting it
        asm volatile("s_waitcnt lgkmcnt(0)" ::: "memory");
        if (kt + 32 < 512) {
            STAGE(kt + 32, p ^ 1);
            asm volatile("s_waitcnt vmcnt(4)" ::: "memory");
        } else {
            asm volatile("s_waitcnt vmcnt(0)" ::: "memory");
        }
        __builtin_amdgcn_sched_barrier(0);

        short* Bl = BW + p * 16384;
        short8 af[4], bf[4];
#pragma unroll
        for (int mi = 0; mi < 4; ++mi) {
            int row = mi * 16 + l16;
            int slot = ((kt >> 3) + quad) ^ (row & 7);
            af[mi] = *(const short8*)(TQ + row * 512 + slot * 8);
        }
#pragma unroll
        for (int ni = 0; ni < 4; ++ni)
            bf[ni] = *(const short8*)(Bl + (ni * 16 + l16) * 32 + quad * 8);
#pragma unroll
        for (int mi = 0; mi < 4; ++mi)
#pragma unroll
            for (int ni = 0; ni < 4; ++ni)
                acc[mi][ni] = __builtin_amdgcn_mfma_f32_16x16x32_bf16(af[mi], bf[ni], acc[mi][ni], 0, 0, 0);
    }
}

// ---------------------------------------------------------------------------
// Staged tail GEMM for the P pass (A staged from global, shared by all waves
// -> keeps the verified barriered schedule; counted vmcnt, swizzled LDS).
// ---------------------------------------------------------------------------
__device__ __forceinline__ void tgemmp(
    const short* __restrict__ Arows, const short* __restrict__ B,
    short* Ls, f32x4 (&acc)[4][4])
{
    const int tid  = threadIdx.x;
    const int lane = tid & 63;
    const int w    = tid >> 6;
    const int l16  = lane & 15, quad = lane >> 4;
    short* BST = Ls + L_BST;
    short* AST = Ls + L_AST;

    auto STAGE = [&](int kt, int p) {
        short* Bl = BST + p * 16384;
#pragma unroll
        for (int j = 0; j < 4; ++j) {
            int lin = j * 512 + tid;
            int r = lin >> 2, gs = lin & 3;
            int g = gs ^ ((r >> 1) & 3);               // source-permuted granule
            gld16(B + (long)r * 512 + kt + g * 8, Bl + j * 4096 + w * 512);
        }
        if (tid < 256) {
            short* Al = AST + p * 2048;
            int r = tid >> 2, gs = tid & 3;
            int g = gs ^ ((r >> 1) & 3);
            gld16(Arows + (long)r * 512 + kt + g * 8, Al + w * 512);
        }
    };

    STAGE(0, 0);
    int p = 0;
    for (int kt = 0; kt < 512; kt += 32, p ^= 1) {
        if (kt + 32 < 512) {
            STAGE(kt + 32, p ^ 1);
            if (w < 4) asm volatile("s_waitcnt vmcnt(5)" ::: "memory");
            else       asm volatile("s_waitcnt vmcnt(4)" ::: "memory");
        } else {
            asm volatile("s_waitcnt vmcnt(0)" ::: "memory");
        }
        __builtin_amdgcn_s_barrier();
        __builtin_amdgcn_sched_barrier(0);

        short* Bl = BST + p * 16384;
        short* Al = AST + p * 2048;
        short8 af[4], bf[4];
#pragma unroll
        for (int mi = 0; mi < 4; ++mi) {
            int row = mi * 16 + l16;
            int slot = quad ^ ((row >> 1) & 3);
            af[mi] = *(const short8*)(Al + row * 32 + slot * 8);
        }
#pragma unroll
        for (int ni = 0; ni < 4; ++ni) {
            int row = w * 64 + ni * 16 + l16;
            int slot = quad ^ ((row >> 1) & 3);
            bf[ni] = *(const short8*)(Bl + row * 32 + slot * 8);
        }
#pragma unroll
        for (int mi = 0; mi < 4; ++mi)
#pragma unroll
            for (int ni = 0; ni < 4; ++ni)
                acc[mi][ni] = __builtin_amdgcn_mfma_f32_16x16x32_bf16(af[mi], bf[ni], acc[mi][ni], 0, 0, 0);
        asm volatile("s_waitcnt lgkmcnt(0)" ::: "memory");
        __builtin_amdgcn_s_barrier();
        __builtin_amdgcn_sched_barrier(0);
    }
}

// Epilogue: wave tile 64x64 -> bf16 rows via eb transpose (verified pattern).
// MODE 0: scores -> L_BST linear [64][512].  MODE 1: tanh -> L_TQ swizzled.
template <int MODE>
__device__ __forceinline__ void epi(f32x4 (&acc)[4][4], short* Ls)
{
    const int tid  = threadIdx.x;
    const int lane = tid & 63;
    const int w    = tid >> 6;
    const int l16  = lane & 15, quad = lane >> 4;
    short* eb = Ls + L_EB + w * 1152;
    const int er = lane >> 2;
    const int ec = (lane & 3) * 16;
#pragma unroll
    for (int mi = 0; mi < 4; ++mi) {
#pragma unroll
        for (int ni = 0; ni < 4; ++ni)
#pragma unroll
            for (int r = 0; r < 4; ++r) {
                float x = acc[mi][ni][r];
                if (MODE == 1) x = tanhf(x);
                eb[(quad * 4 + r) * 72 + ni * 16 + l16] = f2bs(x);
            }
        __builtin_amdgcn_sched_barrier(0);
        short8 v0 = *(const short8*)&eb[er * 72 + ec];
        short8 v1 = *(const short8*)&eb[er * 72 + ec + 8];
        int row = mi * 16 + er;
        if (MODE == 0) {
            short* SC = Ls + L_BST;
            *(short8*)(SC + row * 512 + w * 64 + ec)     = v0;
            *(short8*)(SC + row * 512 + w * 64 + ec + 8) = v1;
        } else {
            int g0 = (w * 64 + ec) >> 3;
            *(short8*)(Ls + L_TQ + row * 512 + ((g0)     ^ (row & 7)) * 8) = v0;
            *(short8*)(Ls + L_TQ + row * 512 + ((g0 + 1) ^ (row & 7)) * 8) = v1;
        }
        __builtin_amdgcn_sched_barrier(0);
    }
}

// ---------------------------------------------------------------------------
// Tail: one block per n=(b,s). Round-5 dataflow; AFT=1 passes now barrier-free
// (wave-private B staging); P pass keeps the verified barriered core.
// ---------------------------------------------------------------------------
__global__ __launch_bounds__(512, 1) void tail_kernel(
    const float* __restrict__ qall, const float* __restrict__ qe,
    const float* __restrict__ b_tq, const float* __restrict__ b_hq,
    const short* __restrict__ tkb, const short* __restrict__ tkWTb,
    const short* __restrict__ WT,
    const int* __restrict__ adj, const int* __restrict__ dup,
    const int* __restrict__ head, const float* __restrict__ b_hk,
    short* __restrict__ Pb, float* __restrict__ out)
{
    __shared__ short Ls[L_TOT];
    const int tid  = threadIdx.x;
    const int lane = tid & 63;
    const int w    = tid >> 6;
    const int l16  = lane & 15, quad = lane >> 4;

    // XCD swizzle: all 32 blocks of one b land on one XCD (round-robin bid%8).
    const int n = (blockIdx.x & 7) * 32 + (blockIdx.x >> 3);
    const int b = n >> 5;
    const int s = n & 31;
    const long rb = (long)n * 64;

    const short* tkb_b  = tkb + (long)b * 262144;
    const short* tkWT_b = tkWTb + (long)b * 262144;
    const short* WT7    = WT + (size_t)7 * 262144;
    const short* WT8    = WT + (size_t)8 * 262144;
    short* Prows = Pb + rb * 512;
    float* HQ = (float*)(Ls + L_HQ);

    // ---- phase 0: build tq rows (swizzled into L_TQ) + hq vector ----
    {
        const int cg = tid & 63;            // col granule
        const int wg = tid >> 6;            // row group (8 rows per wave)
        float4 qd0 = *(const float4*)(qall + (long)n * 2048 + cg * 8);
        float4 qd1 = *(const float4*)(qall + (long)n * 2048 + cg * 8 + 4);
        float4 qh0 = *(const float4*)(qall + (long)(256 + b) * 2048 + 1024 + cg * 8);
        float4 qh1 = *(const float4*)(qall + (long)(256 + b) * 2048 + 1024 + cg * 8 + 4);
        float4 bt0 = *(const float4*)(b_tq + cg * 8);
        float4 bt1 = *(const float4*)(b_tq + cg * 8 + 4);
        float base[8] = {qd0.x + qh0.x + bt0.x, qd0.y + qh0.y + bt0.y,
                         qd0.z + qh0.z + bt0.z, qd0.w + qh0.w + bt0.w,
                         qd1.x + qh1.x + bt1.x, qd1.y + qh1.y + bt1.y,
                         qd1.z + qh1.z + bt1.z, qd1.w + qh1.w + bt1.w};
#pragma unroll
        for (int i = 0; i < 8; ++i) {
            int h = wg * 8 + i;
            const float* er = qe + (long)(b * 64 + h) * 512 + cg * 8;
            float4 e0 = *(const float4*)er;
            float4 e1 = *(const float4*)(er + 4);
            float ev[8] = {e0.x, e0.y, e0.z, e0.w, e1.x, e1.y, e1.z, e1.w};
            short8 o;
#pragma unroll
            for (int u = 0; u < 8; ++u) o[u] = f2bs(eluf(base[u] + ev[u]));
            int slot = cg ^ (h & 7);
            *(short8*)(Ls + L_TQ + h * 512 + slot * 8) = o;
        }
        if (tid < 512) {
            HQ[tid] = eluf(qall[(long)n * 2048 + 512 + tid]
                         + qall[(long)(256 + b) * 2048 + 1536 + tid] + b_hq[tid]);
        }
    }
    __syncthreads();

    f32x4 acc[4][4];
#pragma unroll
    for (int i = 0; i < 4; ++i)
#pragma unroll
        for (int j = 0; j < 4; ++j) { acc[i][j][0]=0.f; acc[i][j][1]=0.f; acc[i][j][2]=0.f; acc[i][j][3]=0.f; }

    // ---- phase A: scores = tq @ tk_b^T -> L_BST linear ----
    tgemmw(Ls + L_TQ, tkb_b, Ls, acc);
    __syncthreads();                       // all waves done with private staging
    epi<0>(acc, Ls);
    __syncthreads();

    // ---- phase A2: mask + row softmax from LDS scores -> Pb ----
    {
        short* SC = Ls + L_BST;
        const int* dupr = dup + ((long)(b * 32 + s)) * 512 + lane * 8;
        int4 d0 = *(const int4*)dupr, d1 = *(const int4*)(dupr + 4);
        int dm[8] = {d0.x, d0.y, d0.z, d0.w, d1.x, d1.y, d1.z, d1.w};
        for (int j = 0; j < 8; ++j) {
            int row = w * 8 + j;
            short8 v8 = *(const short8*)(SC + row * 512 + lane * 8);
            const int* adjr = adj + ((long)(b * 64 + row)) * 512 + lane * 8;
            int4 a0 = *(const int4*)adjr, a1 = *(const int4*)(adjr + 4);
            int am[8] = {a0.x, a0.y, a0.z, a0.w, a1.x, a1.y, a1.z, a1.w};
            float v[8];
            float m = -INFINITY;
#pragma unroll
            for (int i = 0; i < 8; ++i) {
                v[i] = (am[i] && !dm[i]) ? b2f(v8[i]) : -INFINITY;
                m = fmaxf(m, v[i]);
            }
#pragma unroll
            for (int d = 32; d >= 1; d >>= 1) m = fmaxf(m, __shfl_xor(m, d));
            float sum = 0.f;
#pragma unroll
            for (int i = 0; i < 8; ++i) {
                float e = (m == -INFINITY) ? 0.f : expf(v[i] - m);
                v[i] = e; sum += e;
            }
#pragma unroll
            for (int d = 32; d >= 1; d >>= 1) sum += __shfl_xor(sum, d);
            float inv = sum > 0.f ? 1.f / sum : 0.f;
            short8 o;
#pragma unroll
            for (int i = 0; i < 8; ++i) o[i] = f2bs(v[i] * inv);
            *(short8*)(Prows + (long)row * 512 + lane * 8) = o;
        }
    }
    __syncthreads();        // drains P stores (vmcnt in barrier) + frees SC

    // ---- phase B: gh = tanh(tq @ Wtout2^T + P @ tkWT_b^T) ----
#pragma unroll
    for (int i = 0; i < 4; ++i)
#pragma unroll
        for (int j = 0; j < 4; ++j) { acc[i][j][0]=0.f; acc[i][j][1]=0.f; acc[i][j][2]=0.f; acc[i][j][3]=0.f; }
    tgemmw(Ls + L_TQ, WT7, Ls, acc);       // B2: barrier-free, tq live
    __syncthreads();                       // before shared staging of the P pass
    tgemmp(Prows, tkWT_b, Ls, acc);        // B1: stages P from global (barriered)
    epi<1>(acc, Ls);                       // tanh -> gh overwrites L_TQ (swizzled)
    __syncthreads();

    // ---- phase C: hk = elu(gh @ Whk^T + b_hk); hs = hk . hq ----
#pragma unroll
    for (int i = 0; i < 4; ++i)
#pragma unroll
        for (int j = 0; j < 4; ++j) { acc[i][j][0]=0.f; acc[i][j][1]=0.f; acc[i][j][2]=0.f; acc[i][j][3]=0.f; }
    tgemmw(Ls + L_TQ, WT8, Ls, acc);       // A-frags = gh from L_TQ
    __syncthreads();                       // all waves done before F overwrites BST

    float* F     = (float*)(Ls + L_BST);   // f32 scratch over staging region
    float* redf  = F;                      // [8][64]
    float* hal   = F + 512;                // [64]
    float* partf = F + 576;                // [8][512]
    {
        float bv[4], hqv[4];
#pragma unroll
        for (int ni = 0; ni < 4; ++ni) {
            int col = w * 64 + ni * 16 + l16;
            bv[ni]  = b_hk[col];
            hqv[ni] = HQ[col];
        }
#pragma unroll
        for (int mi = 0; mi < 4; ++mi)
#pragma unroll
            for (int r = 0; r < 4; ++r) {
                float p = 0.f;
#pragma unroll
                for (int ni = 0; ni < 4; ++ni)
                    p += eluf(acc[mi][ni][r] + bv[ni]) * hqv[ni];
                p += __shfl_xor(p, 1);
                p += __shfl_xor(p, 2);
                p += __shfl_xor(p, 4);
                p += __shfl_xor(p, 8);
                if (l16 == 0) redf[w * 64 + mi * 16 + quad * 4 + r] = p;
            }
    }
    __syncthreads();

    // ---- head softmax over 64 heads (wave 0) ----
    if (tid < 64) {
        float sv_raw = 0.f;
#pragma unroll
        for (int w2 = 0; w2 < 8; ++w2) sv_raw += redf[w2 * 64 + tid];
        int hv = head[b * 64 + tid];
        unsigned long long ball = __ballot(hv != 0);
        int len = __popcll(ball);
        float sv = (tid < len) ? sv_raw : -INFINITY;
        float m = sv;
#pragma unroll
        for (int d = 32; d >= 1; d >>= 1) m = fmaxf(m, __shfl_xor(m, d));
        float e = expf(sv - m);
        float sum = e;
#pragma unroll
        for (int d = 32; d >= 1; d >>= 1) sum += __shfl_xor(sum, d);
        hal[tid] = e / sum;
    }
    __syncthreads();

    // ---- prob = head_attn . P ----
    {
        const short* tab = Prows + (long)(w * 8) * 512 + lane * 8;
        float a2[8] = {};
#pragma unroll
        for (int k = 0; k < 8; ++k) {
            float a = hal[w * 8 + k];
            short8 tv = *(const short8*)(tab + (long)k * 512);
#pragma unroll
            for (int u = 0; u < 8; ++u) a2[u] += a * b2f(tv[u]);
        }
        float4* pp = (float4*)&partf[w * 512 + lane * 8];
        pp[0] = make_float4(a2[0], a2[1], a2[2], a2[3]);
        pp[1] = make_float4(a2[4], a2[5], a2[6], a2[7]);
    }
    __syncthreads();

    {
        float a = 0.f;
#pragma unroll
        for (int w2 = 0; w2 < 8; ++w2) a += partf[w2 * 512 + tid];
        out[(long)n * 512 + tid] = logf(a + 1e-20f);
    }
}

// ---------------------------------------------------------------------------
// prep (vectorized): float4 casts | 2-rows/block float4 gathers | transposes
// ---------------------------------------------------------------------------
struct WTDesc { const float* src[9]; short* dst[9]; };

__global__ __launch_bounds__(256) void prep(
    const float* __restrict__ dec_out, const float* __restrict__ history,
    short* __restrict__ decb,
    const float* __restrict__ emb, const int* __restrict__ head, const int* __restrict__ tail,
    short* __restrict__ embAll, WTDesc wd)
{
    __shared__ float t[32][33];
    const int id = blockIdx.x, tid = threadIdx.x;
    if (id < 132) {
        int i = (id * 256 + tid) * 4;
        float4 v = (i < 131072) ? *(const float4*)(dec_out + i)
                                : *(const float4*)(history + (i - 131072));
        short4 o;
        o.x = f2bs(v.x); o.y = f2bs(v.y); o.z = f2bs(v.z); o.w = f2bs(v.w);
        *(short4*)(decb + i) = o;
    } else if (id < 132 + 2304) {
        int r = (id - 132) * 2 + (tid >> 7);
        int c4 = (tid & 127) * 4;
        int idx = (r < 512) ? head[r] : tail[r - 512];
        float4 v = *(const float4*)(emb + (long)idx * 512 + c4);
        short4 o;
        o.x = f2bs(v.x); o.y = f2bs(v.y); o.z = f2bs(v.z); o.w = f2bs(v.w);
        *(short4*)(embAll + (long)r * 512 + c4) = o;
    } else {
        int q = id - 2436;
        int z = q >> 8, xy = q & 255;
        int x = xy & 15, y = xy >> 4;
        const float* src = wd.src[z];
        short* dst = wd.dst[z];
        int k0 = y * 32, n0 = x * 32;
        int tx = tid & 31, ty = tid >> 5;
#pragma unroll
        for (int i = 0; i < 32; i += 8)
            t[ty + i][tx] = src[(long)(k0 + ty + i) * 512 + n0 + tx];
        __syncthreads();
#pragma unroll
        for (int i = 0; i < 32; i += 8)
            dst[(long)(n0 + ty + i) * 512 + k0 + tx] = f2bs(t[tx][ty + i]);
    }
}

// qall (48) | qe (16) | tk (128) in one launch (BK=64 core)
__global__ __launch_bounds__(256) void mgemm_multi(
    const short* __restrict__ decb, const short* __restrict__ WTall, float* __restrict__ qall,
    const short* __restrict__ embAll, const short* __restrict__ WTe, float* __restrict__ qe,
    const short* __restrict__ WTk, const float* __restrict__ b_tk, short* __restrict__ tkb)
{
    __shared__ short Ls[16384];
    int id = blockIdx.x;
    if (id < 48) {
        int y = id >> 4, x = id & 15;
        gcore<0, 0>(decb, WTall, nullptr, qall, 2048, 512, y * 128, x * 128, y * 128, Ls);
    } else if (id < 64) {
        int id2 = id - 48, y = id2 >> 2, x = id2 & 3;
        gcore<0, 0>(embAll, WTe, nullptr, qe, 512, 512, y * 128, x * 128, y * 128, Ls);
    } else {
        int id3 = id - 64, y = id3 >> 2, x = id3 & 3;
        gcore<1, 1>(embAll, WTk, b_tk, tkb, 512, 512, 512 + y * 128, x * 128, y * 128, Ls);
    }
}

// tkWT = Wtout1^T @ tk^T per b (128 blocks)
__global__ __launch_bounds__(256) void tkwt_kernel(
    const short* __restrict__ WTo1, const short* __restrict__ tkb, short* __restrict__ tkWTb)
{
    __shared__ short Ls[16384];
    int id = blockIdx.x;
    int z = id >> 4, r = id & 15;
    int x = r & 3, y = r >> 2;
    gcore<0, 1>(WTo1, tkb + (long)z * 262144, nullptr,
                tkWTb + (long)z * 262144, 512, 512, y * 128, x * 128, y * 128, Ls);
}

extern "C" void kernel_launch(void* const* d_in, const int* in_sizes, int n_in,
                              void* d_out, int out_size, void* d_ws, size_t ws_size,
                              hipStream_t stream)
{
    const float* dec_out = (const float*)d_in[0];
    const float* history = (const float*)d_in[1];
    const int*   head    = (const int*)d_in[2];
    const int*   tail    = (const int*)d_in[3];
    const int*   adj     = (const int*)d_in[4];
    const int*   dup     = (const int*)d_in[5];
    const float* emb     = (const float*)d_in[6];
    const float* W_tq    = (const float*)d_in[7];
    const float* b_tq    = (const float*)d_in[8];
    const float* W_tk    = (const float*)d_in[9];
    const float* b_tk    = (const float*)d_in[10];
    const float* W_tout  = (const float*)d_in[11];
    const float* W_hq    = (const float*)d_in[12];
    const float* b_hq    = (const float*)d_in[13];
    const float* W_hk    = (const float*)d_in[14];
    const float* b_hk    = (const float*)d_in[15];
    float* out = (float*)d_out;

    char* ws = (char*)d_ws;
    auto alloc = [&](size_t bytes) -> void* {
        char* p = ws;
        ws += (bytes + 255) & ~(size_t)255;
        return (void*)p;
    };
    short* decb   = (short*)alloc((size_t)384 * 512 * 2);    // dec 0..255, hist 256..263
    short* embAll = (short*)alloc((size_t)4608 * 512 * 2);   // head 0..511, tail 512..4607
    short* WT     = (short*)alloc((size_t)9 * 512 * 512 * 2);
    float* qall   = (float*)alloc((size_t)384 * 2048 * 4);   // [qd|hqp|qh'|hq2']
    float* qe     = (float*)alloc((size_t)512 * 512 * 4);
    short* tkb    = (short*)alloc((size_t)4096 * 512 * 2);
    short* tkWTb  = (short*)alloc((size_t)4096 * 512 * 2);
    short* Pb     = (short*)alloc((size_t)16384 * 512 * 2);  // tail_attn

    // WT slab: 0 Wd^T | 1 Whq1^T | 2 Wtq2^T | 3 Whq2^T | 4 We^T | 5 Wtk^T
    //          6 Wtout1^T | 7 Wtout2^T | 8 Whk^T
    WTDesc wd;
    wd.src[0] = W_tq;               wd.dst[0] = WT;
    wd.src[1] = W_hq;               wd.dst[1] = WT + (size_t)1 * 262144;
    wd.src[2] = W_tq + 512 * 512;   wd.dst[2] = WT + (size_t)2 * 262144;
    wd.src[3] = W_hq + 512 * 512;   wd.dst[3] = WT + (size_t)3 * 262144;
    wd.src[4] = W_tq + 1024 * 512;  wd.dst[4] = WT + (size_t)4 * 262144;
    wd.src[5] = W_tk;               wd.dst[5] = WT + (size_t)5 * 262144;
    wd.src[6] = W_tout;             wd.dst[6] = WT + (size_t)6 * 262144;
    wd.src[7] = W_tout + 512 * 512; wd.dst[7] = WT + (size_t)7 * 262144;
    wd.src[8] = W_hk;               wd.dst[8] = WT + (size_t)8 * 262144;

    // 1: casts / gathers / weight transposes
    prep<<<4740, 256, 0, stream>>>(dec_out, history, decb, emb, head, tail, embAll, wd);
    // 2: qall | qe | tk
    mgemm_multi<<<192, 256, 0, stream>>>(decb, WT, qall, embAll, WT + (size_t)4 * 262144, qe,
                                         WT + (size_t)5 * 262144, b_tk, tkb);
    // 3: tkWT only (tq/hq builds live in the tail)
    tkwt_kernel<<<128, 256, 0, stream>>>(WT + (size_t)6 * 262144, tkb, tkWTb);
    // 4: fused tail (r5 dataflow + wave-private barrier-free B staging)
    tail_kernel<<<256, 512, 0, stream>>>(qall, qe, b_tq, b_hq, tkb, tkWTb, WT,
                                         adj, dup, head, b_hk, Pb, out);
}